// Round 3
// baseline (102.181 us; speedup 1.0000x reference)
//
#include <hip/hip_runtime.h>
#include <math.h>

// Hexagonal sensor photon binning — R2 (resubmit): LUT in LDS + full-occupancy grid.
// Inputs (setup_inputs order):
//   0: x        float32 [N]
//   1: y        float32 [N]
//   2: values   float32 [N]
//   3: lookup   int32   [Q*R]   (square: Q == R == sqrt(count))
//   4: hex_size float32 [1]
//   5: q_offset float32 [1]
//   6: r_offset float32 [1]
//   7: q_min    int32   [1]
//   8: r_min    int32   [1]
//   9: n_pixels int32   [1]
// Output: float32 [n_pixels] segment sums.

__global__ void hex_zero_kernel(float* __restrict__ out, int n) {
    int i = blockIdx.x * blockDim.x + threadIdx.x;
    if (i < n) out[i] = 0.0f;
}

__global__ __launch_bounds__(256) void hex_bin_kernel(
    const float* __restrict__ x,
    const float* __restrict__ y,
    const float* __restrict__ vals,
    const int*   __restrict__ lookup,
    const float* __restrict__ hex_size_p,
    const float* __restrict__ q_off_p,
    const float* __restrict__ r_off_p,
    const int*   __restrict__ q_min_p,
    const int*   __restrict__ r_min_p,
    int Q, int R, int n_pixels, int n_photons,
    float* __restrict__ out)
{
    // LDS layout: [0, n_pixels) = float hist; [n_pixels, n_pixels+Q*R) = int lut
    extern __shared__ float lds[];
    float* hist = lds;
    int*   slut = (int*)(lds + n_pixels);
    const int lut_elems = Q * R;

    for (int i = threadIdx.x; i < n_pixels; i += blockDim.x) hist[i] = 0.0f;
    for (int i = threadIdx.x; i < lut_elems; i += blockDim.x) slut[i] = lookup[i];
    __syncthreads();

    const float inv_h = 1.0f / hex_size_p[0];
    const float qoff  = q_off_p[0];
    const float roff  = r_off_p[0];
    const int   qmin  = q_min_p[0];
    const int   rmin  = r_min_p[0];

    const float cq  = 0.57735026918962576f;  // sqrt(3)/3
    const float c3  = 0.33333333333333333f;  // 1/3
    const float c23 = 0.66666666666666667f;  // 2/3

    auto process = [&](float xf, float yf, float vf) {
        float q = (cq * xf - c3 * yf) * inv_h - qoff;
        float r = (c23 * yf) * inv_h - roff;
        float s = -q - r;
        float qr = rintf(q);   // round-half-even, matches jnp.round
        float rr = rintf(r);
        float sr = rintf(s);
        float qd = fabsf(qr - q);
        float rd = fabsf(rr - r);
        float sd = fabsf(sr - s);
        float q2 = (qd > rd && qd > sd) ? (-rr - sr) : qr;
        float r2 = (rd > qd && rd > sd) ? (-qr - sr) : rr;
        int qi = (int)q2 - qmin;   // truncation == exact for integral floats
        int ri = (int)r2 - rmin;
        if (qi >= 0 && qi < Q && ri >= 0 && ri < R) {
            int p = slut[qi * R + ri];          // random ds_read_b32 — ~free
            if (p >= 0) atomicAdd(&hist[p], vf);  // ds_add_f32 (no return)
        }
    };

    const int tid    = blockIdx.x * blockDim.x + threadIdx.x;
    const int stride = gridDim.x * blockDim.x;
    const int n4     = n_photons >> 2;

    const float4* __restrict__ x4 = (const float4*)x;
    const float4* __restrict__ y4 = (const float4*)y;
    const float4* __restrict__ v4 = (const float4*)vals;

    for (int i = tid; i < n4; i += stride) {
        float4 xv = x4[i];
        float4 yv = y4[i];
        float4 vv = v4[i];
        process(xv.x, yv.x, vv.x);
        process(xv.y, yv.y, vv.y);
        process(xv.z, yv.z, vv.z);
        process(xv.w, yv.w, vv.w);
    }
    // tail (N % 4 != 0)
    for (int i = (n4 << 2) + tid; i < n_photons; i += stride) {
        process(x[i], y[i], vals[i]);
    }

    __syncthreads();
    for (int i = threadIdx.x; i < n_pixels; i += blockDim.x) {
        float h = hist[i];
        if (h != 0.0f) atomicAdd(&out[i], h);
    }
}

extern "C" void kernel_launch(void* const* d_in, const int* in_sizes, int n_in,
                              void* d_out, int out_size, void* d_ws, size_t ws_size,
                              hipStream_t stream) {
    const float* x      = (const float*)d_in[0];
    const float* y      = (const float*)d_in[1];
    const float* vals   = (const float*)d_in[2];
    const int*   lookup = (const int*)d_in[3];
    const float* hexs   = (const float*)d_in[4];
    const float* qoff   = (const float*)d_in[5];
    const float* roff   = (const float*)d_in[6];
    const int*   qmin   = (const int*)d_in[7];
    const int*   rmin   = (const int*)d_in[8];

    const int n_photons = in_sizes[0];
    const int lut_elems = in_sizes[3];
    const int Q = (int)(0.5 + sqrt((double)lut_elems));  // square table (49x49)
    const int R = Q;
    const int n_pixels = out_size;

    float* out = (float*)d_out;

    // d_out is poisoned once and never re-zeroed between replays: zero it here.
    {
        int threads = 256;
        int blocks = (n_pixels + threads - 1) / threads;
        hex_zero_kernel<<<blocks, threads, 0, stream>>>(out, n_pixels);
    }

    // 2048 blocks = 8 blocks/CU * 4 waves = 32 waves/CU (HW cap).
    // LDS: hist (7.2 KB) + LUT (9.6 KB) = 16.8 KB -> 9 blocks/CU LDS-limit, not binding.
    const int threads = 256;
    const int blocks = 2048;
    const size_t lds_bytes = (size_t)(n_pixels + lut_elems) * sizeof(float);
    hex_bin_kernel<<<blocks, threads, lds_bytes, stream>>>(
        x, y, vals, lookup, hexs, qoff, roff, qmin, rmin,
        Q, R, n_pixels, n_photons, out);
}

// Round 5
// 81.337 us; speedup vs baseline: 1.2563x; 1.2563x over previous
//
#include <hip/hip_runtime.h>
#include <math.h>

// Hexagonal sensor photon binning — R4 (resubmit):
//  * per-block LDS histogram (unchanged)
//  * LUT back to GLOBAL (9.6 KB, L1-resident; avoids LDS-pipe contention)
//  * flush spread across P=64 partial rows in d_ws, then a reduce kernel
//    writes out directly (no atomics on the 113-cache-line output)
//  * main loop unrolled 2x float4 (8 photons/iter) for more MLP

#define FLUSH_P 64

__global__ void hex_zero_kernel(float* __restrict__ p, int n) {
    int i = blockIdx.x * blockDim.x + threadIdx.x;
    if (i < n) p[i] = 0.0f;
}

__global__ __launch_bounds__(256) void hex_reduce_kernel(
    const float* __restrict__ partials, float* __restrict__ out, int n_pixels)
{
    int pix = blockIdx.x * blockDim.x + threadIdx.x;
    if (pix >= n_pixels) return;
    float s = 0.0f;
    #pragma unroll 8
    for (int j = 0; j < FLUSH_P; ++j) s += partials[j * n_pixels + pix];
    out[pix] = s;
}

__global__ __launch_bounds__(256) void hex_bin_kernel(
    const float* __restrict__ x,
    const float* __restrict__ y,
    const float* __restrict__ vals,
    const int*   __restrict__ lookup,
    const float* __restrict__ hex_size_p,
    const float* __restrict__ q_off_p,
    const float* __restrict__ r_off_p,
    const int*   __restrict__ q_min_p,
    const int*   __restrict__ r_min_p,
    int Q, int R, int n_pixels, int n_photons,
    float* __restrict__ flush_dst,   // partials (P rows) or out (fallback)
    int use_partials)
{
    extern __shared__ float hist[];  // n_pixels floats
    for (int i = threadIdx.x; i < n_pixels; i += blockDim.x) hist[i] = 0.0f;
    __syncthreads();

    const float inv_h = 1.0f / hex_size_p[0];
    const float qoff  = q_off_p[0];
    const float roff  = r_off_p[0];
    const int   qmin  = q_min_p[0];
    const int   rmin  = r_min_p[0];

    const float cq  = 0.57735026918962576f;  // sqrt(3)/3
    const float c3  = 0.33333333333333333f;  // 1/3
    const float c23 = 0.66666666666666667f;  // 2/3

    auto process = [&](float xf, float yf, float vf) {
        float q = (cq * xf - c3 * yf) * inv_h - qoff;
        float r = (c23 * yf) * inv_h - roff;
        float s = -q - r;
        float qr = rintf(q);   // round-half-even == jnp.round
        float rr = rintf(r);
        float sr = rintf(s);
        float qd = fabsf(qr - q);
        float rd = fabsf(rr - r);
        float sd = fabsf(sr - s);
        float q2 = (qd > rd && qd > sd) ? (-rr - sr) : qr;
        float r2 = (rd > qd && rd > sd) ? (-qr - sr) : rr;
        int qi = (int)q2 - qmin;
        int ri = (int)r2 - rmin;
        if (qi >= 0 && qi < Q && ri >= 0 && ri < R) {
            int p = lookup[qi * R + ri];          // L1-resident 9.6 KB table
            if (p >= 0) atomicAdd(&hist[p], vf);  // ds_add_f32
        }
    };

    const int tid    = blockIdx.x * blockDim.x + threadIdx.x;
    const int stride = gridDim.x * blockDim.x;
    const int n8     = n_photons >> 3;   // groups of 8 photons (2x float4)

    const float4* __restrict__ x4 = (const float4*)x;
    const float4* __restrict__ y4 = (const float4*)y;
    const float4* __restrict__ v4 = (const float4*)vals;

    for (int i = tid; i < n8; i += stride) {
        int a = 2 * i, b = 2 * i + 1;
        float4 xa = x4[a], xb = x4[b];
        float4 ya = y4[a], yb = y4[b];
        float4 va = v4[a], vb = v4[b];
        process(xa.x, ya.x, va.x);
        process(xa.y, ya.y, va.y);
        process(xa.z, ya.z, va.z);
        process(xa.w, ya.w, va.w);
        process(xb.x, yb.x, vb.x);
        process(xb.y, yb.y, vb.y);
        process(xb.z, yb.z, vb.z);
        process(xb.w, yb.w, vb.w);
    }
    // tail (N % 8 != 0)
    for (int i = (n8 << 3) + tid; i < n_photons; i += stride) {
        process(x[i], y[i], vals[i]);
    }

    __syncthreads();
    float* dst = use_partials
        ? flush_dst + (size_t)(blockIdx.x & (FLUSH_P - 1)) * n_pixels
        : flush_dst;
    for (int i = threadIdx.x; i < n_pixels; i += blockDim.x) {
        float h = hist[i];
        if (h != 0.0f) atomicAdd(&dst[i], h);
    }
}

extern "C" void kernel_launch(void* const* d_in, const int* in_sizes, int n_in,
                              void* d_out, int out_size, void* d_ws, size_t ws_size,
                              hipStream_t stream) {
    const float* x      = (const float*)d_in[0];
    const float* y      = (const float*)d_in[1];
    const float* vals   = (const float*)d_in[2];
    const int*   lookup = (const int*)d_in[3];
    const float* hexs   = (const float*)d_in[4];
    const float* qoff   = (const float*)d_in[5];
    const float* roff   = (const float*)d_in[6];
    const int*   qmin   = (const int*)d_in[7];
    const int*   rmin   = (const int*)d_in[8];

    const int n_photons = in_sizes[0];
    const int lut_elems = in_sizes[3];
    const int Q = (int)(0.5 + sqrt((double)lut_elems));  // square table (49x49)
    const int R = Q;
    const int n_pixels = out_size;

    float* out = (float*)d_out;
    float* partials = (float*)d_ws;

    const size_t partial_elems = (size_t)FLUSH_P * (size_t)n_pixels;
    const int use_partials = (ws_size >= partial_elems * sizeof(float)) ? 1 : 0;

    const int threads = 256;
    const int blocks  = 2048;
    const size_t lds_bytes = (size_t)n_pixels * sizeof(float);

    if (use_partials) {
        // zero the partial rows (d_ws is poisoned / stale between launches)
        int zn = (int)partial_elems;
        hex_zero_kernel<<<(zn + 255) / 256, 256, 0, stream>>>(partials, zn);
        hex_bin_kernel<<<blocks, threads, lds_bytes, stream>>>(
            x, y, vals, lookup, hexs, qoff, roff, qmin, rmin,
            Q, R, n_pixels, n_photons, partials, 1);
        hex_reduce_kernel<<<(n_pixels + 255) / 256, 256, 0, stream>>>(
            partials, out, n_pixels);
    } else {
        // fallback: zero out, flush directly with atomics
        hex_zero_kernel<<<(n_pixels + 255) / 256, 256, 0, stream>>>(out, n_pixels);
        hex_bin_kernel<<<blocks, threads, lds_bytes, stream>>>(
            x, y, vals, lookup, hexs, qoff, roff, qmin, rmin,
            Q, R, n_pixels, n_photons, out, 0);
    }
}

// Round 6
// 77.950 us; speedup vs baseline: 1.3108x; 1.0434x over previous
//
#include <hip/hip_runtime.h>
#include <math.h>

// Hexagonal sensor photon binning — R6: closed-form pixel index (no LUT gather).
// The sensor is an analytic hex grid: size=1 => hex_size=1, qa=q, ra=r exactly,
// q_min=r_min=-HEX_R, and lookup[qi][ri] is the q-major enumeration of the hex
// region |q|,|r|,|q+r| <= HEX_R. We compute that enumeration in ~10 int ops
// instead of a random per-lane L1 gather (the R5 serialization suspect).
//  * per-block LDS histogram
//  * flush to FLUSH_P partial rows in d_ws + reduce kernel (no atomics on out)
//  * 2x float4 unrolled main loop

#define FLUSH_P 64

__global__ void hex_zero_kernel(float* __restrict__ p, int n) {
    int i = blockIdx.x * blockDim.x + threadIdx.x;
    if (i < n) p[i] = 0.0f;
}

__global__ __launch_bounds__(256) void hex_reduce_kernel(
    const float* __restrict__ partials, float* __restrict__ out, int n_pixels)
{
    int pix = blockIdx.x * blockDim.x + threadIdx.x;
    if (pix >= n_pixels) return;
    float s = 0.0f;
    #pragma unroll 8
    for (int j = 0; j < FLUSH_P; ++j) s += partials[j * n_pixels + pix];
    out[pix] = s;
}

__global__ __launch_bounds__(256) void hex_bin_kernel(
    const float* __restrict__ x,
    const float* __restrict__ y,
    const float* __restrict__ vals,
    const float* __restrict__ hex_size_p,
    const float* __restrict__ q_off_p,
    const float* __restrict__ r_off_p,
    const int*   __restrict__ q_min_p,
    const int*   __restrict__ r_min_p,
    int Rh,              // hex radius (24); Q = 2*Rh+1
    int n_pixels, int n_photons,
    float* __restrict__ flush_dst,   // partials (P rows) or out (fallback)
    int use_partials)
{
    extern __shared__ float hist[];  // n_pixels floats
    for (int i = threadIdx.x; i < n_pixels; i += blockDim.x) hist[i] = 0.0f;
    __syncthreads();

    const float inv_h = 1.0f / hex_size_p[0];
    const float qoff  = q_off_p[0];
    const float roff  = r_off_p[0];
    const int   qmin  = q_min_p[0];
    const int   rmin  = r_min_p[0];

    const int   twoR = 2 * Rh;
    const int   Tbase = (Rh + 1) * Rh + (Rh * (Rh - 1)) / 2;  // offset at qi==Rh.. base for qi>Rh

    const float cq  = 0.57735026918962576f;  // sqrt(3)/3
    const float c3  = 0.33333333333333333f;  // 1/3
    const float c23 = 0.66666666666666667f;  // 2/3

    auto process = [&](float xf, float yf, float vf) {
        float q = (cq * xf - c3 * yf) * inv_h - qoff;
        float r = (c23 * yf) * inv_h - roff;
        float s = -q - r;
        float qr = rintf(q);   // round-half-even == jnp.round
        float rr = rintf(r);
        float sr = rintf(s);
        float qd = fabsf(qr - q);
        float rd = fabsf(rr - r);
        float sd = fabsf(sr - s);
        float q2 = (qd > rd && qd > sd) ? (-rr - sr) : qr;
        float r2 = (rd > qd && rd > sd) ? (-qr - sr) : rr;
        int qi = (int)q2 - qmin;   // exact for integral floats
        int ri = (int)r2 - rmin;
        // hex-region validity == (in table bounds && lookup != -1)
        int d = qi + ri;
        if (qi >= 0 && qi <= twoR && ri >= 0 && ri <= twoR &&
            d >= Rh && d <= 3 * Rh) {
            int p;
            if (qi <= Rh) {
                p = (Rh + 1) * qi + (qi * (qi - 1)) / 2 + (d - Rh);
            } else {
                int u = qi - Rh;
                p = Tbase + (twoR + 1) * u - (u * (u - 1)) / 2 + ri;
            }
            atomicAdd(&hist[p], vf);  // ds_add_f32 (no return)
        }
    };

    const int tid    = blockIdx.x * blockDim.x + threadIdx.x;
    const int stride = gridDim.x * blockDim.x;
    const int n8     = n_photons >> 3;   // groups of 8 photons (2x float4)

    const float4* __restrict__ x4 = (const float4*)x;
    const float4* __restrict__ y4 = (const float4*)y;
    const float4* __restrict__ v4 = (const float4*)vals;

    for (int i = tid; i < n8; i += stride) {
        int a = 2 * i, b = 2 * i + 1;
        float4 xa = x4[a], xb = x4[b];
        float4 ya = y4[a], yb = y4[b];
        float4 va = v4[a], vb = v4[b];
        process(xa.x, ya.x, va.x);
        process(xa.y, ya.y, va.y);
        process(xa.z, ya.z, va.z);
        process(xa.w, ya.w, va.w);
        process(xb.x, yb.x, vb.x);
        process(xb.y, yb.y, vb.y);
        process(xb.z, yb.z, vb.z);
        process(xb.w, yb.w, vb.w);
    }
    // tail (N % 8 != 0)
    for (int i = (n8 << 3) + tid; i < n_photons; i += stride) {
        process(x[i], y[i], vals[i]);
    }

    __syncthreads();
    float* dst = use_partials
        ? flush_dst + (size_t)(blockIdx.x & (FLUSH_P - 1)) * n_pixels
        : flush_dst;
    for (int i = threadIdx.x; i < n_pixels; i += blockDim.x) {
        float h = hist[i];
        if (h != 0.0f) atomicAdd(&dst[i], h);
    }
}

extern "C" void kernel_launch(void* const* d_in, const int* in_sizes, int n_in,
                              void* d_out, int out_size, void* d_ws, size_t ws_size,
                              hipStream_t stream) {
    const float* x      = (const float*)d_in[0];
    const float* y      = (const float*)d_in[1];
    const float* vals   = (const float*)d_in[2];
    const float* hexs   = (const float*)d_in[4];
    const float* qoff   = (const float*)d_in[5];
    const float* roff   = (const float*)d_in[6];
    const int*   qmin   = (const int*)d_in[7];
    const int*   rmin   = (const int*)d_in[8];

    const int n_photons = in_sizes[0];
    const int lut_elems = in_sizes[3];
    const int Q  = (int)(0.5 + sqrt((double)lut_elems));  // 49
    const int Rh = (Q - 1) / 2;                           // 24
    const int n_pixels = out_size;

    float* out = (float*)d_out;
    float* partials = (float*)d_ws;

    const size_t partial_elems = (size_t)FLUSH_P * (size_t)n_pixels;
    const int use_partials = (ws_size >= partial_elems * sizeof(float)) ? 1 : 0;

    const int threads = 256;
    const int blocks  = 2048;
    const size_t lds_bytes = (size_t)n_pixels * sizeof(float);

    if (use_partials) {
        int zn = (int)partial_elems;
        hex_zero_kernel<<<(zn + 255) / 256, 256, 0, stream>>>(partials, zn);
        hex_bin_kernel<<<blocks, threads, lds_bytes, stream>>>(
            x, y, vals, hexs, qoff, roff, qmin, rmin,
            Rh, n_pixels, n_photons, partials, 1);
        hex_reduce_kernel<<<(n_pixels + 255) / 256, 256, 0, stream>>>(
            partials, out, n_pixels);
    } else {
        hex_zero_kernel<<<(n_pixels + 255) / 256, 256, 0, stream>>>(out, n_pixels);
        hex_bin_kernel<<<blocks, threads, lds_bytes, stream>>>(
            x, y, vals, hexs, qoff, roff, qmin, rmin,
            Rh, n_pixels, n_photons, out, 0);
    }
}